// Round 1
// baseline (87.472 us; speedup 1.0000x reference)
//
#include <hip/hip_runtime.h>
#include <math.h>

#define IMG_S 256
#define NPIX (IMG_S * IMG_S)
#define NFACE 500
#define NCHUNK 8
#define FPC 64               // faces per chunk (8*64 = 512 >= 500)
#define PPT 4                // pixel rows per thread
#define NTILE (IMG_S / PPT)  // 64 row-slabs
#define TSZ 6
#define DIST 2.732f

// w_i = A_i*px + B_i*py + C_i  (edge fn pre-multiplied by 1/area)
struct FaceCoef {
    float A0, B0, C0, A1, B1, C1, A2, B2, C2, Az, Bz, Cz;
};

__device__ __forceinline__ void edge_coef(float ax, float ay, float bx, float by,
                                          float inv, float& A, float& B, float& C) {
    float dy = by - ay;
    float dx = bx - ax;
    A = dy * inv;
    B = -dx * inv;
    C = (ay * dx - ax * dy) * inv;
}

// Shade-side helper: UNCHANGED from the verified absmax-0 kernel (per-view recompute).
__device__ __forceinline__ bool compute_face_bbox(const float* __restrict__ verts,
                                                  const int* __restrict__ faces,
                                                  int f, int view, FaceCoef& fc,
                                                  float& ymin, float& ymax, float& zmax) {
    int i0 = faces[f * 3 + 0];
    int i1 = faces[f * 3 + 1];
    int i2 = faces[f * 3 + 2];

    float v0x = verts[i0 * 3 + 0], v0y = verts[i0 * 3 + 1], v0z = verts[i0 * 3 + 2];
    float v1x = verts[i1 * 3 + 0], v1y = verts[i1 * 3 + 1], v1z = verts[i1 * 3 + 2];
    float v2x = verts[i2 * 3 + 0], v2y = verts[i2 * 3 + 1], v2z = verts[i2 * 3 + 2];

    float p0x, p0y, p0z, p1x, p1y, p1z, p2x, p2y, p2z;
    if (view == 0) {
        p0x = -v0x; p0y = v0y; p0z = DIST - v0z;
        p1x = -v1x; p1y = v1y; p1z = DIST - v1z;
        p2x = -v2x; p2y = v2y; p2z = DIST - v2z;
    } else {
        p0x = v0x; p0y = v0y; p0z = v0z + DIST;
        p1x = v1x; p1y = v1y; p1z = v1z + DIST;
        p2x = v2x; p2y = v2y; p2z = v2z + DIST;
    }

    ymin = fminf(p0y, fminf(p1y, p2y));
    ymax = fmaxf(p0y, fmaxf(p1y, p2y));
    zmax = fmaxf(p0z, fmaxf(p1z, p2z));

    float area = (p1x - p0x) * (p2y - p0y) - (p1y - p0y) * (p2x - p0x);
    bool ok = fabsf(area) > 1e-8f;
    if (!ok) return false;

    float inv = 1.0f / area;
    edge_coef(p1x, p1y, p2x, p2y, inv, fc.A0, fc.B0, fc.C0);
    edge_coef(p2x, p2y, p0x, p0y, inv, fc.A1, fc.B1, fc.C1);
    edge_coef(p0x, p0y, p1x, p1y, inv, fc.A2, fc.B2, fc.C2);
    fc.Az = fc.A0 * p0z + fc.A1 * p1z + fc.A2 * p2z;
    fc.Bz = fc.B0 * p0z + fc.B1 * p1z + fc.B2 * p2z;
    fc.Cz = fc.C0 * p0z + fc.C1 * p1z + fc.C2 * p2z;
    return true;
}

// Merged-view setup: view-1 basis coefficients; view-0 is the exact x-mirror.
// Bit-exactness: mirroring flips dx and area sign EXACTLY, so inv0 = -inv1,
// A0view = -A1view, B/C shared (IEEE negation + 1/(-a) = -(1/a) are exact, and
// fma(-a,-b,c) == fma(a,b,c) bitwise). Only the z-planes differ per view.
struct FaceCoefM {
    float A0, B0, C0, A1, B1, C1, A2, B2, C2;  // view-1 basis
    float Az1, Bz1, Cz1;                        // view-1 z-plane
    float nAz0, Bz0, Cz0;                       // view-0 z-plane (Az negated so both
                                                // views evaluate at the same px)
};

__device__ __forceinline__ bool face_setup_merged(const float* __restrict__ verts,
                                                  const int* __restrict__ faces,
                                                  int f, FaceCoefM& fc,
                                                  float& ymin, float& ymax,
                                                  float& zmax0, float& zmax1) {
    int i0 = faces[f * 3 + 0];
    int i1 = faces[f * 3 + 1];
    int i2 = faces[f * 3 + 2];

    float v0x = verts[i0 * 3 + 0], v0y = verts[i0 * 3 + 1], v0z = verts[i0 * 3 + 2];
    float v1x = verts[i1 * 3 + 0], v1y = verts[i1 * 3 + 1], v1z = verts[i1 * 3 + 2];
    float v2x = verts[i2 * 3 + 0], v2y = verts[i2 * 3 + 1], v2z = verts[i2 * 3 + 2];

    // view-1 depths (eye at -D): z+D ; view-0 depths (eye at +D): D-z
    float r0 = v0z + DIST, r1 = v1z + DIST, r2 = v2z + DIST;
    float q0 = DIST - v0z, q1 = DIST - v1z, q2 = DIST - v2z;

    ymin = fminf(v0y, fminf(v1y, v2y));
    ymax = fmaxf(v0y, fmaxf(v1y, v2y));
    zmax1 = fmaxf(r0, fmaxf(r1, r2));
    zmax0 = fmaxf(q0, fmaxf(q1, q2));

    // view-1 projected coords are (x, y); area identical to the old view==1 path
    float area = (v1x - v0x) * (v2y - v0y) - (v1y - v0y) * (v2x - v0x);
    bool ok = fabsf(area) > 1e-8f;
    if (!ok) return false;

    float inv = 1.0f / area;
    edge_coef(v1x, v1y, v2x, v2y, inv, fc.A0, fc.B0, fc.C0);
    edge_coef(v2x, v2y, v0x, v0y, inv, fc.A1, fc.B1, fc.C1);
    edge_coef(v0x, v0y, v1x, v1y, inv, fc.A2, fc.B2, fc.C2);

    fc.Az1 = fc.A0 * r0 + fc.A1 * r1 + fc.A2 * r2;
    fc.Bz1 = fc.B0 * r0 + fc.B1 * r1 + fc.B2 * r2;
    fc.Cz1 = fc.C0 * r0 + fc.C1 * r1 + fc.C2 * r2;

    // view-0 edge A's are exact negations of view-1 A's (B, C shared)
    float nA0 = -fc.A0, nA1 = -fc.A1, nA2 = -fc.A2;
    float Az0 = nA0 * q0 + nA1 * q1 + nA2 * q2;
    fc.Bz0 = fc.B0 * q0 + fc.B1 * q1 + fc.B2 * q2;
    fc.Cz0 = fc.C0 * q0 + fc.C1 * q1 + fc.C2 * q2;
    fc.nAz0 = -Az0;   // exact: fmaf(px,-Az0,C) == fmaf(-px,Az0,C) bitwise
    return true;
}

__device__ __forceinline__ float pix_x(int ix) {
    return (2.0f * (float)ix + 1.0f - (float)IMG_S) * (1.0f / (float)IMG_S);
}
__device__ __forceinline__ float pix_y(int iy) {
    return -((2.0f * (float)iy + 1.0f - (float)IMG_S) * (1.0f / (float)IMG_S));
}

// ---- Pass 1: merged-view raster. Each thread evaluates barycentrics ONCE and
//      resolves BOTH views (view-1 pixel (row,ix), view-0 pixel (row,255-ix)).
//      Winners merged globally via atomicMin(u64 packed (z,idx)) — order-free. ----
__global__ __launch_bounds__(256) void raster_merged_kernel(
    const float* __restrict__ verts,
    const int*   __restrict__ faces,
    unsigned long long* __restrict__ zbuf)   // [2][NPIX], pre-set to 0xFF..
{
    __shared__ float4 sc[FPC][4];
    __shared__ int    scount;

    const int tile  = blockIdx.x;    // rows [tile*PPT, tile*PPT+PPT)
    const int chunk = blockIdx.y;
    const int fbase = chunk * FPC;

    const float py_top = pix_y(tile * PPT);
    const float py_bot = pix_y(tile * PPT + PPT - 1);

    // ---- setup + cull + compact (first wave, one face per lane) ----
    if (threadIdx.x < 64) {
        bool keep = false;
        FaceCoefM c;
        int fi = fbase + (int)threadIdx.x;
        if (fi < NFACE) {
            float ymin, ymax, zx0, zx1;
            bool ok = face_setup_merged(verts, faces, fi, c, ymin, ymax, zx0, zx1);
            keep = ok && (ymax >= py_bot) && (ymin <= py_top) &&
                   (zx0 > 0.0f || zx1 > 0.0f);
        }
        unsigned long long bal = __ballot(keep);
        int pos = __popcll(bal & ((1ull << (threadIdx.x & 63)) - 1ull));
        if (keep) {
            sc[pos][0] = make_float4(c.A0, c.B0, c.C0, c.A1);
            sc[pos][1] = make_float4(c.B1, c.C1, c.A2, c.B2);
            sc[pos][2] = make_float4(c.C2, c.Az1, c.Bz1, c.Cz1);
            sc[pos][3] = make_float4(c.nAz0, c.Bz0, c.Cz0,
                                     __int_as_float(fbase + (int)threadIdx.x));
        }
        if (threadIdx.x == 0) scount = (int)__popcll(bal);
    }
    __syncthreads();
    const int cnt = scount;

    const int ix = threadIdx.x;
    const float px = pix_x(ix);
    float py[PPT];
    #pragma unroll
    for (int k = 0; k < PPT; ++k) py[k] = pix_y(tile * PPT + k);

    float bz0[PPT], bz1[PPT];
    int   bj0[PPT], bj1[PPT];
    #pragma unroll
    for (int k = 0; k < PPT; ++k) {
        bz0[k] = INFINITY; bz1[k] = INFINITY;
        bj0[k] = -1;       bj1[k] = -1;
    }

    for (int j = 0; j < cnt; ++j) {
        float4 q0 = sc[j][0];
        float4 q1 = sc[j][1];
        float4 q2 = sc[j][2];
        float4 q3 = sc[j][3];
        // hoist px-dependent parts (once per face)
        float d0 = fmaf(px, q0.x, q0.z);   // A0*px + C0
        float d1 = fmaf(px, q0.w, q1.y);   // A1*px + C1
        float d2 = fmaf(px, q1.z, q2.x);   // A2*px + C2
        float e1 = fmaf(px, q2.y, q2.w);   // Az1*px + Cz1
        float e0 = fmaf(px, q3.x, q3.z);   // (-Az0)*px + Cz0  == Az0*(-px)+Cz0
        #pragma unroll
        for (int k = 0; k < PPT; ++k) {
            float w0 = fmaf(q0.y, py[k], d0);
            float w1 = fmaf(q1.x, py[k], d1);
            float w2 = fmaf(q1.w, py[k], d2);
            float wmin = fminf(w0, fminf(w1, w2));
            float z1 = fmaf(q2.z, py[k], e1);
            float z0 = fmaf(q3.y, py[k], e0);
            // strict < keeps first (smallest) j on ties — same as before
            float s1 = fminf(z1, bz1[k] - z1);
            bool  c1 = (wmin >= 0.0f) && (s1 > 0.0f);
            bz1[k] = c1 ? z1 : bz1[k];
            bj1[k] = c1 ? j : bj1[k];
            float s0 = fminf(z0, bz0[k] - z0);
            bool  c0 = (wmin >= 0.0f) && (s0 > 0.0f);
            bz0[k] = c0 ? z0 : bz0[k];
            bj0[k] = c0 ? j : bj0[k];
        }
    }

    #pragma unroll
    for (int k = 0; k < PPT; ++k) {
        const int row = tile * PPT + k;
        if (bj1[k] >= 0) {
            int fidx = __float_as_int(sc[bj1[k]][3].w);
            unsigned long long packed =
                ((unsigned long long)__float_as_uint(bz1[k]) << 32) |
                (unsigned int)fidx;
            atomicMin(&zbuf[(size_t)NPIX + row * IMG_S + ix], packed);
        }
        if (bj0[k] >= 0) {
            int fidx = __float_as_int(sc[bj0[k]][3].w);
            unsigned long long packed =
                ((unsigned long long)__float_as_uint(bz0[k]) << 32) |
                (unsigned int)fidx;
            atomicMin(&zbuf[row * IMG_S + (IMG_S - 1 - ix)], packed);
        }
    }
}

// ---- Pass 2: read merged zbuf, shade winner (bit-exact recompute), loss,
//      block-reduce, one atomicAdd per block into out (pre-zeroed) ----
__global__ __launch_bounds__(256) void shade_loss_kernel(
    const float* __restrict__ verts,
    const int*   __restrict__ faces,
    const float* __restrict__ tex,
    const float* __restrict__ ref0,
    const float* __restrict__ ref1,
    const unsigned long long* __restrict__ zbuf,
    float* __restrict__ out)
{
    __shared__ float red[4];
    const int gid  = blockIdx.x * blockDim.x + threadIdx.x;  // 0..131071
    const int view = gid >> 16;
    const int pix  = gid & (NPIX - 1);

    unsigned long long best = zbuf[(size_t)view * NPIX + pix];

    float c0 = 0.0f, c1 = 0.0f, c2 = 0.0f;
    if (best != ~0ull) {
        int fidx = (int)(best & 0xFFFFFFFFu);
        FaceCoef fcw;
        float ymin, ymax, zmax;
        compute_face_bbox(verts, faces, fidx, view, fcw, ymin, ymax, zmax);
        const float px = pix_x(pix & (IMG_S - 1));
        const float py = pix_y(pix >> 8);
        float w0 = fmaf(fcw.B0, py, fmaf(px, fcw.A0, fcw.C0));
        float w1 = fmaf(fcw.B1, py, fmaf(px, fcw.A1, fcw.C1));
        float w2 = fmaf(fcw.B2, py, fmaf(px, fcw.A2, fcw.C2));
        int t0 = (int)fminf(fmaxf(rintf(w0 * (float)(TSZ - 1)), 0.0f), (float)(TSZ - 1));
        int t1 = (int)fminf(fmaxf(rintf(w1 * (float)(TSZ - 1)), 0.0f), (float)(TSZ - 1));
        int t2 = (int)fminf(fmaxf(rintf(w2 * (float)(TSZ - 1)), 0.0f), (float)(TSZ - 1));
        int flat = ((fidx * TSZ + t0) * TSZ + t1) * TSZ + t2;
        const float* t = tex + (long)flat * 3;
        c0 = tanhf(t[0]);
        c1 = tanhf(t[1]);
        c2 = tanhf(t[2]);
    }

    const float* __restrict__ ref = (view == 0) ? ref0 : ref1;
    float d0 = c0 - ref[0 * NPIX + pix];
    float d1 = c1 - ref[1 * NPIX + pix];
    float d2 = c2 - ref[2 * NPIX + pix];
    float acc = fmaf(d0, d0, fmaf(d1, d1, d2 * d2));

    for (int off = 32; off > 0; off >>= 1)
        acc += __shfl_down(acc, off, 64);
    int lane = threadIdx.x & 63;
    int wid = threadIdx.x >> 6;
    if (lane == 0) red[wid] = acc;
    __syncthreads();
    if (threadIdx.x == 0)
        atomicAdd(out, 0.5f * (red[0] + red[1] + red[2] + red[3]));
}

extern "C" void kernel_launch(void* const* d_in, const int* in_sizes, int n_in,
                              void* d_out, int out_size, void* d_ws, size_t ws_size,
                              hipStream_t stream) {
    const float* verts = (const float*)d_in[0];
    const int*   faces = (const int*)d_in[1];
    const float* tex   = (const float*)d_in[2];
    const float* ref0  = (const float*)d_in[3];
    const float* ref1  = (const float*)d_in[4];
    float* out = (float*)d_out;

    unsigned long long* zbuf = (unsigned long long*)d_ws;   // 2*65536*8 = 1 MB

    hipMemsetAsync(zbuf, 0xFF, (size_t)2 * NPIX * sizeof(unsigned long long), stream);
    hipMemsetAsync(out, 0, sizeof(float), stream);

    dim3 grid1(NTILE, NCHUNK);   // (64, 8) = 512 blocks, views merged
    raster_merged_kernel<<<grid1, 256, 0, stream>>>(verts, faces, zbuf);

    const int shade_blocks = (2 * NPIX) / 256;   // 512
    shade_loss_kernel<<<shade_blocks, 256, 0, stream>>>(verts, faces, tex, ref0, ref1,
                                                        zbuf, out);
}